// Round 1
// baseline (238.589 us; speedup 1.0000x reference)
//
#include <hip/hip_runtime.h>

namespace {

constexpr int NQ = 12;
constexpr int DIM = 1 << NQ;   // 4096
constexpr int NL = 4;
constexpr int THREADS = 256;

struct c32 { float r, i; };

__device__ __forceinline__ c32 cmul(c32 a, c32 b) {
    return { a.r * b.r - a.i * b.i, a.r * b.i + a.i * b.r };
}
__device__ __forceinline__ c32 cadd(c32 a, c32 b) { return { a.r + b.r, a.i + b.i }; }

// XOR bank swizzle: keeps every pass's wave access pattern bank-equivalent to contiguous
__device__ __forceinline__ int physidx(int s) { return s ^ ((s >> 4) & 15); }

// gray->binary (suffix XOR): t such that bin2gray(t) == s; CNOT ladder is new[t] = old[t^(t>>1)]
__device__ __forceinline__ int g2b(int s) {
    s ^= s >> 1; s ^= s >> 2; s ^= s >> 4; s ^= s >> 8;
    return s;
}

// apply 2x2 gate m to local bit BP of the 16-amplitude register group
template<int BP>
__device__ __forceinline__ void applyGate(c32 v[16], const c32 m[4]) {
    #pragma unroll
    for (int mi = 0; mi < 8; ++mi) {
        const int i0 = ((mi >> BP) << (BP + 1)) | (mi & ((1 << BP) - 1));
        const int i1 = i0 | (1 << BP);
        c32 a = v[i0], bb = v[i1];
        v[i0] = cadd(cmul(m[0], a), cmul(m[1], bb));
        v[i1] = cadd(cmul(m[2], a), cmul(m[3], bb));
    }
}

__global__ __launch_bounds__(THREADS)
void qcirc_kernel(const float* __restrict__ x, const float* __restrict__ thetas,
                  float* __restrict__ out) {
    __shared__ float2 amp[DIM];            // 32 KB state (swizzled layout)
    __shared__ float4 Vs[NL * NQ * 2];     // 48 fused 2x2 gates, 2 float4 each
    __shared__ float red[4];

    const int tid = threadIdx.x;
    const int b = blockIdx.x;

    // feature-map matrix M = RZ(x2) * RY(x1)  (same for all qubits, batch-dependent)
    const float xv = x[b];
    const float x1 = asinf(xv);
    const float x2 = acosf(xv * xv);
    const float cy = cosf(0.5f * x1), sy = sinf(0.5f * x1);
    const float cz = cosf(0.5f * x2), sz = sinf(0.5f * x2);
    // e^{-i x2/2} = (cz, -sz)
    const c32 M00 = {  cz * cy, -sz * cy };
    const c32 M01 = { -cz * sy,  sz * sy };
    const c32 M10 = {  cz * sy,  sz * sy };
    const c32 M11 = {  cz * cy,  sz * cy };

    // init |0...0>
    for (int s = tid; s < DIM; s += THREADS) amp[s] = make_float2(0.f, 0.f);
    if (tid == 0) amp[0] = make_float2(1.f, 0.f);   // physidx(0)==0

    // fused per-(l,q) gate V = RX(t2) RZ(t1) RX(t0) * M
    if (tid < NL * NQ) {
        const float* th = thetas + tid * 3;
        const float h0 = 0.5f * th[0], h1 = 0.5f * th[1], h2 = 0.5f * th[2];
        const float c0 = cosf(h0), s0 = sinf(h0);
        const float c1 = cosf(h1), s1 = sinf(h1);
        const float c2 = cosf(h2), s2 = sinf(h2);
        // RX(t) = [[(c,0),(0,-s)],[(0,-s),(c,0)]] ; RZ(t) = diag((c,-s),(c,s))
        const c32 z0 = { c1, -s1 }, z1 = { c1, s1 };
        const c32 X00 = { c0, 0.f }, X01 = { 0.f, -s0 };
        const c32 A00 = cmul(z0, X00), A01 = cmul(z0, X01);
        const c32 A10 = cmul(z1, X01), A11 = cmul(z1, X00);
        const c32 Y00 = { c2, 0.f }, Y01 = { 0.f, -s2 };
        const c32 U00 = cadd(cmul(Y00, A00), cmul(Y01, A10));
        const c32 U01 = cadd(cmul(Y00, A01), cmul(Y01, A11));
        const c32 U10 = cadd(cmul(Y01, A00), cmul(Y00, A10));
        const c32 U11 = cadd(cmul(Y01, A01), cmul(Y00, A11));
        const c32 V00 = cadd(cmul(U00, M00), cmul(U01, M10));
        const c32 V01 = cadd(cmul(U00, M01), cmul(U01, M11));
        const c32 V10 = cadd(cmul(U10, M00), cmul(U11, M10));
        const c32 V11 = cadd(cmul(U10, M01), cmul(U11, M11));
        Vs[tid * 2]     = make_float4(V00.r, V00.i, V01.r, V01.i);
        Vs[tid * 2 + 1] = make_float4(V10.r, V10.i, V11.r, V11.i);
    }
    __syncthreads();

    for (int l = 0; l < NL; ++l) {
        #pragma unroll
        for (int k = 0; k < 3; ++k) {
            const int p = 8 - 4 * k;              // field bits p..p+3 <-> qubits 4k..4k+3
            const int low = tid & ((1 << p) - 1);
            const int high = tid >> p;
            const int base = (high << (p + 4)) | low;

            c32 V[4][4];
            #pragma unroll
            for (int j = 0; j < 4; ++j) {
                const float4 a = Vs[(l * NQ + 4 * k + j) * 2];
                const float4 c = Vs[(l * NQ + 4 * k + j) * 2 + 1];
                V[j][0] = { a.x, a.y }; V[j][1] = { a.z, a.w };
                V[j][2] = { c.x, c.y }; V[j][3] = { c.z, c.w };
            }

            c32 v[16];
            #pragma unroll
            for (int j = 0; j < 16; ++j) {
                const float2 t = amp[physidx(base | (j << p))];
                v[j] = { t.x, t.y };
            }

            // qubit 4k+j acts on local bit 3-j
            applyGate<3>(v, V[0]);
            applyGate<2>(v, V[1]);
            applyGate<1>(v, V[2]);
            applyGate<0>(v, V[3]);

            if (k < 2) {
                #pragma unroll
                for (int j = 0; j < 16; ++j)
                    amp[physidx(base | (j << p))] = make_float2(v[j].r, v[j].i);
                __syncthreads();
            } else {
                // fuse the CNOT-ladder permutation into this pass's write phase:
                // held value belongs to source index s; its destination is t = g2b(s)
                __syncthreads();   // all group reads complete before scattered writes
                #pragma unroll
                for (int j = 0; j < 16; ++j) {
                    const int s = base | j;       // p == 0 here
                    amp[physidx(g2b(s))] = make_float2(v[j].r, v[j].i);
                }
                __syncthreads();
            }
        }
    }

    // <Z^{\otimes n}> = sum_s parity(s) * |amp[s]|^2
    float acc = 0.f;
    #pragma unroll
    for (int it = 0; it < DIM / THREADS; ++it) {
        const int s = tid + it * THREADS;
        const float2 a = amp[physidx(s)];
        const float m2 = a.x * a.x + a.y * a.y;
        acc += (__popc(s) & 1) ? -m2 : m2;
    }
    #pragma unroll
    for (int off = 32; off > 0; off >>= 1) acc += __shfl_down(acc, off, 64);
    if ((tid & 63) == 0) red[tid >> 6] = acc;
    __syncthreads();
    if (tid == 0) out[b] = red[0] + red[1] + red[2] + red[3];
}

} // namespace

extern "C" void kernel_launch(void* const* d_in, const int* in_sizes, int n_in,
                              void* d_out, int out_size, void* d_ws, size_t ws_size,
                              hipStream_t stream) {
    const float* x      = (const float*)d_in[0];
    const float* thetas = (const float*)d_in[1];
    float* out          = (float*)d_out;
    const int batch = in_sizes[0];
    qcirc_kernel<<<batch, THREADS, 0, stream>>>(x, thetas, out);
}

// Round 2
// 116.994 us; speedup vs baseline: 2.0393x; 2.0393x over previous
//
#include <hip/hip_runtime.h>

namespace {

constexpr int NQ = 12;
constexpr int DIM = 1 << NQ;   // 4096
constexpr int NL = 4;
constexpr int THREADS = 256;

struct c32 { float r, i; };

__device__ __forceinline__ c32 cmul(c32 a, c32 b) {
    return { fmaf(a.r, b.r, -(a.i * b.i)), fmaf(a.r, b.i, a.i * b.r) };
}

// butterfly: (x,y) <- (m00 x + m01 y, m10 x + m11 y), 16 VALU ops (4x {mul,fma,fma,fma})
__device__ __forceinline__ void bf(c32& x, c32& y,
                                   c32 m00, c32 m01, c32 m10, c32 m11) {
    const c32 a = x, b = y;
    x.r = fmaf(m00.r, a.r, fmaf(-m00.i, a.i, fmaf(m01.r, b.r, -(m01.i * b.i))));
    x.i = fmaf(m00.r, a.i, fmaf( m00.i, a.r, fmaf(m01.r, b.i,   m01.i * b.r)));
    y.r = fmaf(m10.r, a.r, fmaf(-m10.i, a.i, fmaf(m11.r, b.r, -(m11.i * b.i))));
    y.i = fmaf(m10.r, a.i, fmaf( m10.i, a.r, fmaf(m11.r, b.i,   m11.i * b.r)));
}

// apply 2x2 gate to local bit BP of the 16-amplitude register group
template<int BP>
__device__ __forceinline__ void applyGate(c32 v[16], const c32 m[4]) {
    #pragma unroll
    for (int mi = 0; mi < 8; ++mi) {
        const int i0 = ((mi >> BP) << (BP + 1)) | (mi & ((1 << BP) - 1));
        const int i1 = i0 | (1 << BP);
        bf(v[i0], v[i1], m[0], m[1], m[2], m[3]);
    }
}

// ---- XOR-linear address algebra (element indices, float2 units) ----
// Layouts: L0(s) = s ^ ((s>>4)&15) ^ 15*s4   (state at layer boundaries)
//          L1(s) = L0(s ^ ((s&15)<<8))       (between pass0 and pass1)
//          L2(s) = L1(s ^ (((s>>8)&15)<<4))  (between pass1 and pass2)
// All are GF(2)-linear => addr = thread_base XOR compile-time-const[j].
__device__ __forceinline__ int L0f(int s) { const int u = (s >> 4) & 15; return s ^ u ^ (15 * (u & 1)); }
__device__ __forceinline__ int g2b12(int s) { s ^= s >> 1; s ^= s >> 2; s ^= s >> 4; s ^= s >> 8; return s; }
__host__ __device__ constexpr int g2b4(int j) { return j ^ (j >> 1) ^ (j >> 2) ^ (j >> 3); }
__host__ __device__ constexpr int CEc(int m) { return (m << 4) | (m ^ (15 * (m & 1))); }  // pass1 r/w const
__host__ __device__ constexpr int QEc(int j) { return (j << 8) | j; }                      // pass2 read const

__device__ __forceinline__ void loadGates(const float4* Vs, int gbase, c32 V[4][4]) {
    #pragma unroll
    for (int g = 0; g < 4; ++g) {
        const float4 a = Vs[(gbase + g) * 2];
        const float4 c = Vs[(gbase + g) * 2 + 1];
        V[g][0] = { a.x, a.y }; V[g][1] = { a.z, a.w };
        V[g][2] = { c.x, c.y }; V[g][3] = { c.z, c.w };
    }
}

__global__ __launch_bounds__(THREADS)
void qcirc_kernel(const float* __restrict__ x, const float* __restrict__ thetas,
                  float* __restrict__ out) {
    __shared__ float2 amp[DIM];            // 32 KB state (per-pass swizzled layouts)
    __shared__ float4 Vs[NL * NQ * 2];     // 48 fused 2x2 gates
    __shared__ float red[4];

    const int tid = threadIdx.x;
    const int b = blockIdx.x;

    // ---- fused gate construction: V = RX(t2) RZ(t1) RX(t0) RZ(x2) RY(x1) ----
    const float xv = x[b];
    const float x1 = asinf(xv);
    const float x2 = acosf(xv * xv);
    const float cy = cosf(0.5f * x1), sy = sinf(0.5f * x1);
    const float cz = cosf(0.5f * x2), sz = sinf(0.5f * x2);
    const c32 M00 = {  cz * cy, -sz * cy };
    const c32 M01 = { -cz * sy,  sz * sy };
    const c32 M10 = {  cz * sy,  sz * sy };
    const c32 M11 = {  cz * cy,  sz * cy };

    if (tid < NL * NQ) {
        const float* th = thetas + tid * 3;
        const float h0 = 0.5f * th[0], h1 = 0.5f * th[1], h2 = 0.5f * th[2];
        const float c0 = cosf(h0), s0 = sinf(h0);
        const float c1 = cosf(h1), s1 = sinf(h1);
        const float c2 = cosf(h2), s2 = sinf(h2);
        const c32 z0 = { c1, -s1 }, z1 = { c1, s1 };
        const c32 X00 = { c0, 0.f }, X01 = { 0.f, -s0 };
        const c32 A00 = cmul(z0, X00), A01 = cmul(z0, X01);
        const c32 A10 = cmul(z1, X01), A11 = cmul(z1, X00);
        const c32 Y00 = { c2, 0.f }, Y01 = { 0.f, -s2 };
        const c32 U00 = { Y00.r*A00.r - Y00.i*A00.i + Y01.r*A10.r - Y01.i*A10.i,
                          Y00.r*A00.i + Y00.i*A00.r + Y01.r*A10.i + Y01.i*A10.r };
        const c32 U01 = { Y00.r*A01.r - Y00.i*A01.i + Y01.r*A11.r - Y01.i*A11.i,
                          Y00.r*A01.i + Y00.i*A01.r + Y01.r*A11.i + Y01.i*A11.r };
        const c32 U10 = { Y01.r*A00.r - Y01.i*A00.i + Y00.r*A10.r - Y00.i*A10.i,
                          Y01.r*A00.i + Y01.i*A00.r + Y00.r*A10.i + Y00.i*A10.r };
        const c32 U11 = { Y01.r*A01.r - Y01.i*A01.i + Y00.r*A11.r - Y00.i*A11.i,
                          Y01.r*A01.i + Y01.i*A01.r + Y00.r*A11.i + Y00.i*A11.r };
        const c32 V00 = { U00.r*M00.r - U00.i*M00.i + U01.r*M10.r - U01.i*M10.i,
                          U00.r*M00.i + U00.i*M00.r + U01.r*M10.i + U01.i*M10.r };
        const c32 V01 = { U00.r*M01.r - U00.i*M01.i + U01.r*M11.r - U01.i*M11.i,
                          U00.r*M01.i + U00.i*M01.r + U01.r*M11.i + U01.i*M11.r };
        const c32 V10 = { U10.r*M00.r - U10.i*M00.i + U11.r*M10.r - U11.i*M10.i,
                          U10.r*M00.i + U10.i*M00.r + U11.r*M10.i + U11.i*M10.r };
        const c32 V11 = { U10.r*M01.r - U10.i*M01.i + U11.r*M11.r - U11.i*M11.i,
                          U10.r*M01.i + U10.i*M01.r + U11.r*M11.i + U11.i*M11.r };
        Vs[tid * 2]     = make_float4(V00.r, V00.i, V01.r, V01.i);
        Vs[tid * 2 + 1] = make_float4(V10.r, V10.i, V11.r, V11.i);
    }

    // ---- per-thread address bases (all loops use base XOR compile-time const) ----
    const int Lo = tid & 15, Hh = tid >> 4;
    const int R0 = L0f(tid);                    // pass0 read:  amp[R0 + (j<<8)]
    const int wrE0 = R0 ^ (Lo << 8);            // pass0 write: amp[wrE0 ^ (j<<8)]
    const int e1base = ((Hh ^ Lo) << 8) | Lo;   // pass1 read:  amp[e1base ^ CEc(j)]
    const int wrE1 = e1base ^ CEc(Hh);          // pass1 write: amp[wrE1 ^ CEc(j)]
    const int LH = Lo ^ Hh;
    const int P2e = (Hh << 8) | (LH << 4) | (LH ^ (15 * (LH & 1)));  // pass2 read ^ QEc(j)
    const int Ae = L0f(g2b12(tid << 4));        // gray write:  amp[Ae ^ g2b4(j)]

    __syncthreads();

    // ---- layer 0: state is a tensor product; compute directly, then gray-scatter ----
    {
        c32 C = { 1.f, 0.f };
        #pragma unroll
        for (int q = 0; q < 8; ++q) {
            const float4 r0 = Vs[q * 2];
            const float4 r1 = Vs[q * 2 + 1];
            const bool bit = (tid >> (7 - q)) & 1;
            const c32 e = { bit ? r1.x : r0.x, bit ? r1.y : r0.y };
            C = cmul(C, e);
        }
        c32 e8[2], e9[2], e10[2], e11[2];
        {
            float4 a, c;
            a = Vs[8*2];  c = Vs[8*2+1];  e8[0]  = { a.x, a.y }; e8[1]  = { c.x, c.y };
            a = Vs[9*2];  c = Vs[9*2+1];  e9[0]  = { a.x, a.y }; e9[1]  = { c.x, c.y };
            a = Vs[10*2]; c = Vs[10*2+1]; e10[0] = { a.x, a.y }; e10[1] = { c.x, c.y };
            a = Vs[11*2]; c = Vs[11*2+1]; e11[0] = { a.x, a.y }; e11[1] = { c.x, c.y };
        }
        c32 CP[4], Q[4];
        #pragma unroll
        for (int a = 0; a < 2; ++a)
            #pragma unroll
            for (int d = 0; d < 2; ++d) {
                CP[a * 2 + d] = cmul(cmul(C, e8[a]), e9[d]);   // qubit8 bit=a (j3), qubit9 bit=d (j2)
                Q[a * 2 + d]  = cmul(e10[a], e11[d]);          // qubit10 bit=a (j1), qubit11 bit=d (j0)
            }
        #pragma unroll
        for (int j = 0; j < 16; ++j) {
            const c32 v = cmul(CP[j >> 2], Q[j & 3]);
            amp[Ae ^ g2b4(j)] = make_float2(v.r, v.i);
        }
    }
    __syncthreads();

    // ---- layers 1..3: three register-blocked passes each ----
    #pragma unroll 1
    for (int l = 1; l < NL; ++l) {
        // pass 0: qubits 0..3 (s bits 8..11), read L0, write L1 (same slots per thread)
        {
            c32 V[4][4];
            loadGates(Vs, l * NQ + 0, V);
            c32 v[16];
            #pragma unroll
            for (int j = 0; j < 16; ++j) {
                const float2 t = amp[R0 + (j << 8)];
                v[j] = { t.x, t.y };
            }
            applyGate<3>(v, V[0]); applyGate<2>(v, V[1]);
            applyGate<1>(v, V[2]); applyGate<0>(v, V[3]);
            #pragma unroll
            for (int j = 0; j < 16; ++j)
                amp[wrE0 ^ (j << 8)] = make_float2(v[j].r, v[j].i);
            __syncthreads();
        }
        // pass 1: qubits 4..7 (s bits 4..7), read L1, write L2 (same slots per thread)
        {
            c32 V[4][4];
            loadGates(Vs, l * NQ + 4, V);
            c32 v[16];
            #pragma unroll
            for (int j = 0; j < 16; ++j) {
                const float2 t = amp[e1base ^ CEc(j)];
                v[j] = { t.x, t.y };
            }
            applyGate<3>(v, V[0]); applyGate<2>(v, V[1]);
            applyGate<1>(v, V[2]); applyGate<0>(v, V[3]);
            #pragma unroll
            for (int j = 0; j < 16; ++j)
                amp[wrE1 ^ CEc(j)] = make_float2(v[j].r, v[j].i);
            __syncthreads();
        }
        // pass 2: qubits 8..11 (s bits 0..3), read L2, gray-scatter into L0
        {
            c32 V[4][4];
            loadGates(Vs, l * NQ + 8, V);
            c32 v[16];
            #pragma unroll
            for (int j = 0; j < 16; ++j) {
                const float2 t = amp[P2e ^ QEc(j)];
                v[j] = { t.x, t.y };
            }
            applyGate<3>(v, V[0]); applyGate<2>(v, V[1]);
            applyGate<1>(v, V[2]); applyGate<0>(v, V[3]);
            __syncthreads();   // all reads done before cross-thread scatter
            #pragma unroll
            for (int j = 0; j < 16; ++j)
                amp[Ae ^ g2b4(j)] = make_float2(v[j].r, v[j].i);
            __syncthreads();
        }
    }

    // ---- <Z...Z>: sum parity(s)*|amp|^2 ; state is in L0 layout ----
    float acc = 0.f;
    #pragma unroll
    for (int it = 0; it < DIM / THREADS; ++it) {
        const float2 a = amp[R0 + (it << 8)];
        const float m2 = fmaf(a.x, a.x, a.y * a.y);
        if (__popc(it) & 1) acc -= m2; else acc += m2;
    }
    if (__popc(tid) & 1) acc = -acc;
    #pragma unroll
    for (int off = 32; off > 0; off >>= 1) acc += __shfl_down(acc, off, 64);
    if ((tid & 63) == 0) red[tid >> 6] = acc;
    __syncthreads();
    if (tid == 0) out[b] = red[0] + red[1] + red[2] + red[3];
}

} // namespace

extern "C" void kernel_launch(void* const* d_in, const int* in_sizes, int n_in,
                              void* d_out, int out_size, void* d_ws, size_t ws_size,
                              hipStream_t stream) {
    const float* x      = (const float*)d_in[0];
    const float* thetas = (const float*)d_in[1];
    float* out          = (float*)d_out;
    const int batch = in_sizes[0];
    qcirc_kernel<<<batch, THREADS, 0, stream>>>(x, thetas, out);
}

// Round 3
// 116.608 us; speedup vs baseline: 2.0461x; 1.0033x over previous
//
#include <hip/hip_runtime.h>

namespace {

constexpr int NQ = 12;
constexpr int DIM = 1 << NQ;   // 4096
constexpr int THREADS = 256;

struct c32 { float r, i; };

__device__ __forceinline__ c32 cmul(c32 a, c32 b) {
    return { fmaf(a.r, b.r, -(a.i * b.i)), fmaf(a.r, b.i, a.i * b.r) };
}

// butterfly: (x,y) <- (m00 x + m01 y, m10 x + m11 y), 16 FMA-class ops
__device__ __forceinline__ void bf(c32& x, c32& y, c32 m00, c32 m01, c32 m10, c32 m11) {
    const c32 a = x, b = y;
    x.r = fmaf(m00.r, a.r, fmaf(-m00.i, a.i, fmaf(m01.r, b.r, -(m01.i * b.i))));
    x.i = fmaf(m00.r, a.i, fmaf( m00.i, a.r, fmaf(m01.r, b.i,   m01.i * b.r)));
    y.r = fmaf(m10.r, a.r, fmaf(-m10.i, a.i, fmaf(m11.r, b.r, -(m11.i * b.i))));
    y.i = fmaf(m10.r, a.i, fmaf( m10.i, a.r, fmaf(m11.r, b.i,   m11.i * b.r)));
}

template<int BP>
__device__ __forceinline__ void applyGate(c32 v[16], const c32 m[4]) {
    #pragma unroll
    for (int mi = 0; mi < 8; ++mi) {
        const int i0 = ((mi >> BP) << (BP + 1)) | (mi & ((1 << BP) - 1));
        const int i1 = i0 | (1 << BP);
        bf(v[i0], v[i1], m[0], m[1], m[2], m[3]);
    }
}

// gamma^k: k-fold CNOT-ladder index fold, gamma(t) = t ^ (t>>1); order 16 on 12 bits
__host__ __device__ constexpr int G(int t, int k) {
    for (int i = 0; i < k; ++i) t = (t ^ (t >> 1)) & 0xFFF;
    return t;
}
// layout shear C (involution): low4 ^= psi(n1) ^ phi(n2).
// psi: t4->2 t5->4 t6->8 t7->6 ; phi: t8->0xA t9->0xC (t10,t11 -> 0).
// Chosen so C.G^k gives rank-4 lane->bankpair maps for passes 0/1 (b64) and
// bit0-clean rank-3 lane->bankquad maps for pass 2 / layer-0 (b128), k=0..3.
__host__ __device__ constexpr int Cm(int t) {
    int lo = 0;
    if (t & 0x010) lo ^= 0x2;
    if (t & 0x020) lo ^= 0x4;
    if (t & 0x040) lo ^= 0x8;
    if (t & 0x080) lo ^= 0x6;
    if (t & 0x100) lo ^= 0xA;
    if (t & 0x200) lo ^= 0xC;
    return t ^ lo;
}
// readout weight: w(e) = parity(gamma^{-4}(C(e))); gamma^{-4} = gamma^{12}
__host__ __device__ constexpr int maskE_calc() {
    int m = 0;
    for (int i = 0; i < 12; ++i) {
        int v = G(Cm(1 << i), 12), p = 0;
        while (v) { p ^= (v & 1); v >>= 1; }
        if (p) m |= (1 << i);
    }
    return m;
}
constexpr int MASKE = maskE_calc();

__device__ __forceinline__ void loadGates(const float4* Vs, int gbase, c32 V[4][4]) {
    #pragma unroll
    for (int g = 0; g < 4; ++g) {
        const float4 a = Vs[(gbase + g) * 2];
        const float4 c = Vs[(gbase + g) * 2 + 1];
        V[g][0] = { a.x, a.y }; V[g][1] = { a.z, a.w };
        V[g][2] = { c.x, c.y }; V[g][3] = { c.z, c.w };
    }
}

// one gate layer (layers 1..3), K = layer index = gamma power for this boundary
template<int K>
__device__ __forceinline__ void doLayer(float2* amp, float4* a4, const float4* Vs, int tid) {
    const int Lo = tid & 15, Hh = tid >> 4;

    // ---- pass 0: qubits 0-3 (t bits 11-8); CNOT fold is in the address constants ----
    {
        c32 V[4][4];
        loadGates(Vs, K * NQ + 0, V);
        const int beta = Cm(G(tid, K));
        c32 v[16];
        #pragma unroll
        for (int j = 0; j < 16; ++j) {
            const float2 t = amp[beta ^ Cm(G(j << 8, K))];
            v[j] = { t.x, t.y };
        }
        applyGate<3>(v, V[0]); applyGate<2>(v, V[1]); applyGate<1>(v, V[2]); applyGate<0>(v, V[3]);
        #pragma unroll
        for (int j = 0; j < 16; ++j)
            amp[beta ^ Cm(G(j << 8, K))] = make_float2(v[j].r, v[j].i);
        __syncthreads();
    }
    // ---- pass 1: qubits 4-7 (t bits 7-4) ----
    {
        c32 V[4][4];
        loadGates(Vs, K * NQ + 4, V);
        const int beta = Cm(G((Hh << 8) | Lo, K));
        c32 v[16];
        #pragma unroll
        for (int j = 0; j < 16; ++j) {
            const float2 t = amp[beta ^ Cm(G(j << 4, K))];
            v[j] = { t.x, t.y };
        }
        applyGate<3>(v, V[0]); applyGate<2>(v, V[1]); applyGate<1>(v, V[2]); applyGate<0>(v, V[3]);
        #pragma unroll
        for (int j = 0; j < 16; ++j)
            amp[beta ^ Cm(G(j << 4, K))] = make_float2(v[j].r, v[j].i);
        __syncthreads();
    }
    // ---- pass 2: qubits 8-11 (t bits 3-0), float4-paired along the gamma-fixed direction ----
    {
        c32 V[4][4];
        loadGates(Vs, K * NQ + 8, V);
        const int beta = Cm(G((Hh << 8) | (Lo << 4), K));   // bit0 == 0 by construction
        c32 v[16];
        #pragma unroll
        for (int m = 0; m < 8; ++m) {
            const int gg = Cm(G(2 * m, K));                 // compile-time constant
            const float4 F = a4[(beta ^ (gg & ~1)) >> 1];
            if (gg & 1) { v[2*m+1] = { F.x, F.y }; v[2*m]   = { F.z, F.w }; }
            else        { v[2*m]   = { F.x, F.y }; v[2*m+1] = { F.z, F.w }; }
        }
        applyGate<3>(v, V[0]); applyGate<2>(v, V[1]); applyGate<1>(v, V[2]); applyGate<0>(v, V[3]);
        #pragma unroll
        for (int m = 0; m < 8; ++m) {
            const int gg = Cm(G(2 * m, K));
            float4 F;
            if (gg & 1) F = make_float4(v[2*m+1].r, v[2*m+1].i, v[2*m].r,   v[2*m].i);
            else        F = make_float4(v[2*m].r,   v[2*m].i,   v[2*m+1].r, v[2*m+1].i);
            a4[(beta ^ (gg & ~1)) >> 1] = F;
        }
        __syncthreads();
    }
}

__global__ __launch_bounds__(THREADS)
void qcirc_kernel(const float* __restrict__ x, const float* __restrict__ thetas,
                  float* __restrict__ out) {
    __shared__ alignas(16) float2 amp[DIM];   // 32 KB state, layout C.gamma^l
    __shared__ float4 Vs[4 * NQ * 2];         // 48 fused 2x2 gates
    __shared__ float red[4];
    float4* a4 = reinterpret_cast<float4*>(amp);

    const int tid = threadIdx.x;
    const int b = blockIdx.x;

    // ---- fused gate construction: V = RX(t2) RZ(t1) RX(t0) RZ(x2) RY(x1) ----
    const float xv = x[b];
    const float x1 = asinf(xv);
    const float x2 = acosf(xv * xv);
    const float cy = cosf(0.5f * x1), sy = sinf(0.5f * x1);
    const float cz = cosf(0.5f * x2), sz = sinf(0.5f * x2);
    const c32 M00 = {  cz * cy, -sz * cy };
    const c32 M01 = { -cz * sy,  sz * sy };
    const c32 M10 = {  cz * sy,  sz * sy };
    const c32 M11 = {  cz * cy,  sz * cy };

    if (tid < 4 * NQ) {
        const float* th = thetas + tid * 3;
        const float h0 = 0.5f * th[0], h1 = 0.5f * th[1], h2 = 0.5f * th[2];
        const float c0 = cosf(h0), s0 = sinf(h0);
        const float c1 = cosf(h1), s1 = sinf(h1);
        const float c2 = cosf(h2), s2 = sinf(h2);
        const c32 z0 = { c1, -s1 }, z1 = { c1, s1 };
        const c32 X00 = { c0, 0.f }, X01 = { 0.f, -s0 };
        const c32 A00 = cmul(z0, X00), A01 = cmul(z0, X01);
        const c32 A10 = cmul(z1, X01), A11 = cmul(z1, X00);
        const c32 Y00 = { c2, 0.f }, Y01 = { 0.f, -s2 };
        const c32 U00 = { Y00.r*A00.r - Y00.i*A00.i + Y01.r*A10.r - Y01.i*A10.i,
                          Y00.r*A00.i + Y00.i*A00.r + Y01.r*A10.i + Y01.i*A10.r };
        const c32 U01 = { Y00.r*A01.r - Y00.i*A01.i + Y01.r*A11.r - Y01.i*A11.i,
                          Y00.r*A01.i + Y00.i*A01.r + Y01.r*A11.i + Y01.i*A11.r };
        const c32 U10 = { Y01.r*A00.r - Y01.i*A00.i + Y00.r*A10.r - Y00.i*A10.i,
                          Y01.r*A00.i + Y01.i*A00.r + Y00.r*A10.i + Y00.i*A10.r };
        const c32 U11 = { Y01.r*A01.r - Y01.i*A01.i + Y00.r*A11.r - Y00.i*A11.i,
                          Y01.r*A01.i + Y01.i*A01.r + Y00.r*A11.i + Y00.i*A11.r };
        const c32 V00 = { U00.r*M00.r - U00.i*M00.i + U01.r*M10.r - U01.i*M10.i,
                          U00.r*M00.i + U00.i*M00.r + U01.r*M10.i + U01.i*M10.r };
        const c32 V01 = { U00.r*M01.r - U00.i*M01.i + U01.r*M11.r - U01.i*M11.i,
                          U00.r*M01.i + U00.i*M01.r + U01.r*M11.i + U01.i*M11.r };
        const c32 V10 = { U10.r*M00.r - U10.i*M00.i + U11.r*M10.r - U11.i*M10.i,
                          U10.r*M00.i + U10.i*M00.r + U11.r*M10.i + U11.i*M10.r };
        const c32 V11 = { U10.r*M01.r - U10.i*M01.i + U11.r*M11.r - U11.i*M11.i,
                          U10.r*M01.i + U10.i*M01.r + U11.r*M11.i + U11.i*M11.r };
        Vs[tid * 2]     = make_float4(V00.r, V00.i, V01.r, V01.i);
        Vs[tid * 2 + 1] = make_float4(V10.r, V10.i, V11.r, V11.i);
    }
    __syncthreads();

    // ---- layer 0: tensor product computed directly, written at layout C ----
    {
        c32 C = { 1.f, 0.f };
        #pragma unroll
        for (int q = 0; q < 8; ++q) {
            const float4 r0 = Vs[q * 2];
            const float4 r1 = Vs[q * 2 + 1];
            const bool bit = (tid >> (7 - q)) & 1;
            const c32 e = { bit ? r1.x : r0.x, bit ? r1.y : r0.y };
            C = cmul(C, e);
        }
        c32 e8[2], e9[2], e10[2], e11[2];
        {
            float4 a, c;
            a = Vs[8*2];  c = Vs[8*2+1];  e8[0]  = { a.x, a.y }; e8[1]  = { c.x, c.y };
            a = Vs[9*2];  c = Vs[9*2+1];  e9[0]  = { a.x, a.y }; e9[1]  = { c.x, c.y };
            a = Vs[10*2]; c = Vs[10*2+1]; e10[0] = { a.x, a.y }; e10[1] = { c.x, c.y };
            a = Vs[11*2]; c = Vs[11*2+1]; e11[0] = { a.x, a.y }; e11[1] = { c.x, c.y };
        }
        c32 CP[4], Q[4];
        #pragma unroll
        for (int aa = 0; aa < 2; ++aa)
            #pragma unroll
            for (int d = 0; d < 2; ++d) {
                CP[aa * 2 + d] = cmul(cmul(C, e8[aa]), e9[d]);
                Q[aa * 2 + d]  = cmul(e10[aa], e11[d]);
            }
        c32 w[16];
        #pragma unroll
        for (int j = 0; j < 16; ++j) w[j] = cmul(CP[j >> 2], Q[j & 3]);
        const int beta = Cm(tid << 4);        // even; Cm(j)=j for j<16
        #pragma unroll
        for (int m = 0; m < 8; ++m)
            a4[(beta ^ (2 * m)) >> 1] =
                make_float4(w[2*m].r, w[2*m].i, w[2*m+1].r, w[2*m+1].i);
    }
    __syncthreads();

    // ---- layers 1..3 (CNOT ladders folded into addressing) ----
    doLayer<1>(amp, a4, Vs, tid);
    doLayer<2>(amp, a4, Vs, tid);
    doLayer<3>(amp, a4, Vs, tid);

    // ---- readout: weight = parity(MASKE & e); final CNOT folded into MASKE ----
    float acc = 0.f;
    #pragma unroll
    for (int it = 0; it < 8; ++it) {
        const int pe = (it << 9) | (tid << 1);
        const float4 F = a4[pe >> 1];
        const float m0 = fmaf(F.x, F.x, F.y * F.y);
        const float m1 = fmaf(F.z, F.z, F.w * F.w);
        acc += (__popc(pe & MASKE) & 1) ? -m0 : m0;
        acc += (__popc((pe | 1) & MASKE) & 1) ? -m1 : m1;
    }
    #pragma unroll
    for (int off = 32; off > 0; off >>= 1) acc += __shfl_down(acc, off, 64);
    if ((tid & 63) == 0) red[tid >> 6] = acc;
    __syncthreads();
    if (tid == 0) out[b] = red[0] + red[1] + red[2] + red[3];
}

} // namespace

extern "C" void kernel_launch(void* const* d_in, const int* in_sizes, int n_in,
                              void* d_out, int out_size, void* d_ws, size_t ws_size,
                              hipStream_t stream) {
    const float* x      = (const float*)d_in[0];
    const float* thetas = (const float*)d_in[1];
    float* out          = (float*)d_out;
    const int batch = in_sizes[0];
    qcirc_kernel<<<batch, THREADS, 0, stream>>>(x, thetas, out);
}